// Round 8
// baseline (601.456 us; speedup 1.0000x reference)
//
#include <hip/hip_runtime.h>
#include <hip/hip_bf16.h>

// Round-8: LAYOUT-TRANSFORM DECOMPOSITION. Evidence r0-r7: dispatch dur pinned
// 219-252us while HBM bytes (655->317MB), occupancy (19->38%), load width,
// batching, pipelining, tile width ALL varied => ~85-90% of cycles are stalls
// not attributable to any measured pipe. Last untested invariant: the in-kernel
// NCHW->c-innermost transpose+convert staging chain. This round removes it:
//  (1) pack_xt: x (N,C,H,W) f32 -> xt (N,HW,64c) bf16. Pure streaming pre-pass
//      (205MB R + 103MB W), coalesced both sides.
//  (2) conv3x3_nhwc: A-layout in global == MFMA frag layout. Staging is pure
//      global_load_lds dwordx4 (no VALU transpose, no cvt, no VGPR round trip).
//      Bank-swizzle (pixel stride 128B = 32-way conflict otherwise) applied by
//      permuting the PER-LANE GLOBAL SOURCE (gll LDS dest is linear, guide #21):
//      slot_stored(pixel,s) = global slot s^(pixel&7); ds_read applies same XOR.
//      Tile: 2 out rows x 112 w x 64 kout; 448 thr / 7 waves; wave = 32 pixels
//      (1 m-tile) x 64 kout, acc[2]=32 regs. LDS [4][114][64c] = 58368B ->
//      2 blocks/CU. Grid 3584 = 16img x 112ht x 2wb, XCD-chunked (448 = 2 img).
// Workspace: wt (73.7KB) + xt (102.8MB); falls back to round-3 kernel (best
// measured, 219us) if ws too small.

typedef __attribute__((ext_vector_type(8)))  short   short8;
typedef __attribute__((ext_vector_type(8)))  unsigned short ushort8;
typedef __attribute__((ext_vector_type(16))) float   float16_t;

#define HW (224 * 224)

typedef __attribute__((address_space(1))) const void gas_void;
typedef __attribute__((address_space(3))) void las_void;

__device__ __forceinline__ unsigned short f2bf(float f) {
  __hip_bfloat16 h = __float2bfloat16(f);  // RNE
  return *reinterpret_cast<unsigned short*>(&h);
}

// ---- pre-kernel A: Wt[tap][kout][c] bf16 <- W[kout][c][tap] fp32 ----
__global__ void build_wt(const float* __restrict__ W, unsigned short* __restrict__ wt) {
  int i = blockIdx.x * 256 + threadIdx.x;  // 0 .. 36863
  if (i < 9 * 64 * 64) {
    int tap = i >> 12;
    int rem = i & 4095;
    int nn  = rem >> 6;
    int c   = rem & 63;
    wt[i] = f2bf(W[(nn * 64 + c) * 9 + tap]);
  }
}

// ---- pre-kernel B: xt[n][p][c] bf16 <- x[n][c][p] f32 (p = h*224+w) ----
__global__ __launch_bounds__(256, 4) void pack_xt(
    const float* __restrict__ x, unsigned short* __restrict__ xt) {
  const int n = blockIdx.x / 196;
  const int p = (blockIdx.x - n * 196) * 256 + threadIdx.x;  // 0..50175 exact
  const float* xp = x + (size_t)n * 64 * HW + p;
  unsigned short* op = xt + ((size_t)n * HW + p) * 64;
#pragma unroll
  for (int c0 = 0; c0 < 64; c0 += 8) {
    float v[8];
#pragma unroll
    for (int j = 0; j < 8; ++j) v[j] = xp[(size_t)(c0 + j) * HW];
    ushort8 pk;
#pragma unroll
    for (int j = 0; j < 8; ++j) pk[j] = f2bf(v[j]);
    *reinterpret_cast<ushort8*>(op + c0) = pk;
  }
}

// ---- main kernel: NHWC-in, NCHW-out implicit GEMM ----
__global__ __launch_bounds__(448, 3) void conv3x3_nhwc(
    const unsigned short* __restrict__ xt, const unsigned short* __restrict__ wt,
    const float* __restrict__ bias, float* __restrict__ out) {
  // [row(4)][col(114)][c(64)] bf16, 16B slots XOR-swizzled by pixel&7.
  __shared__ __align__(16) unsigned short xs[4 * 114 * 64];  // 58368 B

  // XCD-chunked swizzle: 3584 blocks, chunk of 448 = exactly 2 images per XCD.
  const int bid = blockIdx.x;
  const int t   = (bid & 7) * 448 + (bid >> 3);
  const int wb2 = t & 1;            // 0: w 0..111, 1: w 112..223
  const int rest = t >> 1;
  const int ht  = rest % 112;
  const int img = rest / 112;
  const int h0  = ht * 2;
  const int wb  = wb2 * 112;

  const int tid = threadIdx.x;
  const int lane = tid & 63, wave = tid >> 6;   // wave 0..6
  const int ln31 = lane & 31, lhi = lane >> 5;

  const unsigned short* xti = xt + (size_t)img * HW * 64;

  // ---- stage: 56 chunks x 1KB via global_load_lds (8 pixels/chunk) ----
  // left  (wb2=0): lds cols 1..112 <- gw 0..111 ; tail col113<-gw112 ; pad col0
  // right (wb2=1): lds cols 0..111 <- gw 111..222; tail col112<-gw223; pad col113
  const int lds_px0 = wb2 ? 0 : 1;
  const int gw_ch0  = wb2 ? 111 : 0;
  const int pxl  = lane >> 3;   // 0..7 pixel within chunk
  const int slot = lane & 7;    // 16B slot within pixel
  for (int c = wave; c < 56; c += 7) {
    const int r  = c / 14;
    const int ch = c - r * 14;
    const int gh = h0 - 1 + r;
    const int base_px = r * 114 + lds_px0 + ch * 8;   // linear lds pixel index
    unsigned short* lbase = &xs[(size_t)base_px * 64];
    if ((unsigned)gh < 224u) {
      const int lpx = base_px + pxl;
      const int gp  = gw_ch0 + ch * 8 + pxl;
      const unsigned short* gsrc = xti + ((size_t)(gh * 224 + gp)) * 64
                                       + (size_t)((slot ^ (lpx & 7)) * 8);
      __builtin_amdgcn_global_load_lds((gas_void*)gsrc, (las_void*)lbase, 16, 0, 0);
    } else {
      // vertical halo: zero this 1KB chunk (swizzle-invariant)
      uint4 z = make_uint4(0u, 0u, 0u, 0u);
      *reinterpret_cast<uint4*>(&xs[(size_t)base_px * 64 + (size_t)lane * 8]) = z;
    }
  }
  // ---- fixup: tail pixel + pad pixel per row (64 thread-tasks) ----
  if (tid < 64) {
    const int r     = tid >> 4;
    const int which = (tid >> 3) & 1;   // 0: pad, 1: tail
    const int sl    = tid & 7;
    const int col   = which ? (wb2 ? 112 : 113) : (wb2 ? 113 : 0);
    const int gwT   = wb2 ? 223 : 112;
    const int gh    = h0 - 1 + r;
    const int lin   = r * 114 + col;
    unsigned short* dst = &xs[(size_t)lin * 64 + (size_t)((sl ^ (lin & 7)) * 8)];
    uint4 v = make_uint4(0u, 0u, 0u, 0u);
    if (which && ((unsigned)gh < 224u)) {
      v = *reinterpret_cast<const uint4*>(
          xti + ((size_t)(gh * 224 + gwT)) * 64 + (size_t)sl * 8);
    }
    *reinterpret_cast<uint4*>(dst) = v;
  }
  __syncthreads();

  // ---- MFMA: 4 ksteps x 9 taps x 2 nb = 72 per wave ----
  const int p    = wave * 32 + ln31;          // 0..223 output pixel of this wave
  const int orow = (p >= 112) ? 1 : 0;
  const int ocol = p - orow * 112;

  float16_t acc[2];
  acc[0] = 0.f; acc[1] = 0.f;

#pragma unroll
  for (int ks = 0; ks < 4; ++ks) {
    const int sl = ks * 2 + lhi;              // 16B slot = c-range within pixel
#pragma unroll
    for (int r = 0; r < 3; ++r) {
#pragma unroll
      for (int s = 0; s < 3; ++s) {
        const int tap = r * 3 + s;
        const short8 b0 = *reinterpret_cast<const short8*>(
            wt + ((tap * 64 + ln31) * 64 + ks * 16 + lhi * 8));
        const short8 b1 = *reinterpret_cast<const short8*>(
            wt + ((tap * 64 + 32 + ln31) * 64 + ks * 16 + lhi * 8));
        const int lin = (orow + r) * 114 + (ocol + s);
        const short8 a = *reinterpret_cast<const short8*>(
            &xs[(size_t)lin * 64 + (size_t)((sl ^ (lin & 7)) * 8)]);
        acc[0] = __builtin_amdgcn_mfma_f32_32x32x16_bf16(a, b0, acc[0], 0, 0, 0);
        acc[1] = __builtin_amdgcn_mfma_f32_32x32x16_bf16(a, b1, acc[1], 0, 0, 0);
      }
    }
  }

  // ---- epilogue: D col(ln31)=kout, row m=(reg&3)+8*(reg>>2)+4*lhi = pixel ----
  // float4 groups are 4-aligned in m; row break at m=16 (wave 3) is 4-aligned
  // -> no straddle. (r7-proven store form.)
#pragma unroll
  for (int nb = 0; nb < 2; ++nb) {
    const int chn = nb * 32 + ln31;
    const float bv = bias[chn];
    float* ob = out + ((size_t)img * 64 + chn) * (size_t)HW;
#pragma unroll
    for (int q = 0; q < 4; ++q) {
      const int m   = 8 * q + 4 * lhi;
      const int pix = wave * 32 + m;
      const int r2  = (pix >= 112) ? 1 : 0;
      const int cc  = pix - r2 * 112;
      float4 v;
      v.x = acc[nb][4 * q + 0] + bv;
      v.y = acc[nb][4 * q + 1] + bv;
      v.z = acc[nb][4 * q + 2] + bv;
      v.w = acc[nb][4 * q + 3] + bv;
      *reinterpret_cast<float4*>(ob + (size_t)(h0 + r2) * 224 + wb + cc) = v;
    }
  }
}

// ---- fallback 1: round-3 kernel (best measured in-place: 219us) ----
__global__ __launch_bounds__(256, 2) void conv3x3_mfma_tile(
    const float* __restrict__ x, const unsigned short* __restrict__ wt,
    const float* __restrict__ bias, float* __restrict__ out) {
  __shared__ __align__(16) unsigned short xs[18 * 8 * 34 * 8];
  const int bid = blockIdx.x;
  const int t   = (bid & 7) * 196 + (bid >> 3);
  const int bx  = t % 7;
  const int rem_t = t / 7;
  const int by  = rem_t % 14;
  const int img = rem_t / 14;
  const int w0  = bx * 32;
  const int h0  = by * 16;
  const int tid = threadIdx.x;
  const int lane = tid & 63, wave = tid >> 6;
  const int ln31 = lane & 31, lhi = lane >> 5;
  const float* xn = x + (size_t)img * 64 * HW;
  for (int i = tid; i < 18 * 8 * 10 * 0 + 18 * 8 * 34; i += 256) {
    int h   = i / (8 * 34);
    int rem = i - h * (8 * 34);
    int cg  = rem / 34;
    int w   = rem - cg * 34;
    int gh = h0 - 1 + h;
    int gw = w0 - 1 + w;
    ushort8 pk;
    if ((unsigned)gh < 224u && (unsigned)gw < 224u) {
      const float* pp = xn + (size_t)cg * 8 * HW + gh * 224 + gw;
#pragma unroll
      for (int j = 0; j < 8; ++j) pk[j] = f2bf(pp[(size_t)j * HW]);
    } else {
#pragma unroll
      for (int j = 0; j < 8; ++j) pk[j] = 0;
    }
    *reinterpret_cast<ushort8*>(&xs[i * 8]) = pk;
  }
  __syncthreads();
  const int row0 = wave * 4;
  float16_t acc[4][2];
#pragma unroll
  for (int rb = 0; rb < 4; ++rb)
#pragma unroll
    for (int nb = 0; nb < 2; ++nb) acc[rb][nb] = 0.f;
#pragma unroll
  for (int r = 0; r < 3; ++r) {
#pragma unroll
    for (int s = 0; s < 3; ++s) {
      const int tap = r * 3 + s;
      short8 bq[4][2];
#pragma unroll
      for (int ks = 0; ks < 4; ++ks)
#pragma unroll
        for (int nb = 0; nb < 2; ++nb)
          bq[ks][nb] = *reinterpret_cast<const short8*>(
              wt + ((tap * 64 + nb * 32 + ln31) * 64 + ks * 16 + lhi * 8));
#pragma unroll
      for (int ks = 0; ks < 4; ++ks) {
        const int cg = ks * 2 + lhi;
#pragma unroll
        for (int rb = 0; rb < 4; ++rb) {
          const int hidx = row0 + rb + r;
          const int widx = ln31 + s;
          const short8 a = *reinterpret_cast<const short8*>(
              &xs[(((hidx * 8) + cg) * 34 + widx) * 8]);
          acc[rb][0] = __builtin_amdgcn_mfma_f32_32x32x16_bf16(a, bq[ks][0], acc[rb][0], 0, 0, 0);
          acc[rb][1] = __builtin_amdgcn_mfma_f32_32x32x16_bf16(a, bq[ks][1], acc[rb][1], 0, 0, 0);
        }
      }
    }
  }
#pragma unroll
  for (int rb = 0; rb < 4; ++rb) {
    const int h = h0 + row0 + rb;
#pragma unroll
    for (int nb = 0; nb < 2; ++nb) {
      const int ch = nb * 32 + ln31;
      const float bv = bias[ch];
      float* op = out + (((size_t)img * 64 + ch) * 224 + h) * 224 + w0;
#pragma unroll
      for (int q = 0; q < 4; ++q) {
        const int wloc = 8 * q + 4 * lhi;
        float4 v;
        v.x = acc[rb][nb][4 * q + 0] + bv;
        v.y = acc[rb][nb][4 * q + 1] + bv;
        v.z = acc[rb][nb][4 * q + 2] + bv;
        v.w = acc[rb][nb][4 * q + 3] + bv;
        *reinterpret_cast<float4*>(op + wloc) = v;
      }
    }
  }
}

// ---- fallback 2: direct fp32 ----
#define TW 32
#define TH 32
#define KB 16
#define PXT 4
__global__ __launch_bounds__(256) void conv3x3_direct(
    const float* __restrict__ x, const float* __restrict__ wgt,
    const float* __restrict__ bias, float* __restrict__ out) {
  __shared__ float xsf[34 * 35];
  const int tx = blockIdx.x % 7, ty = blockIdx.x / 7;
  const int k0 = blockIdx.y * KB, n = blockIdx.z;
  const int w0 = tx * TW, h0 = ty * TH;
  const int tid = threadIdx.x;
  const int tw = tid & 7, th = tid >> 3;
  float acc[KB][PXT];
#pragma unroll
  for (int k = 0; k < KB; ++k)
#pragma unroll
    for (int p = 0; p < PXT; ++p) acc[k][p] = 0.f;
  const float* xn = x + (size_t)n * 64 * HW;
  for (int c = 0; c < 64; ++c) {
    const float* xc = xn + (size_t)c * HW;
    for (int i = tid; i < 34 * 34; i += 256) {
      int row = i / 34, col = i - row * 34;
      int gh = h0 - 1 + row, gw = w0 - 1 + col;
      float v = 0.f;
      if (gh >= 0 && gh < 224 && gw >= 0 && gw < 224) v = xc[gh * 224 + gw];
      xsf[row * 35 + col] = v;
    }
    __syncthreads();
    float in[3][6];
#pragma unroll
    for (int r = 0; r < 3; ++r)
#pragma unroll
      for (int q = 0; q < 6; ++q) in[r][q] = xsf[(th + r) * 35 + tw * PXT + q];
    const float* wc = wgt + ((size_t)k0 * 64 + c) * 9;
#pragma unroll
    for (int k = 0; k < KB; ++k) {
      const float* wk = wc + (size_t)k * 64 * 9;
#pragma unroll
      for (int r = 0; r < 3; ++r)
#pragma unroll
        for (int s = 0; s < 3; ++s) {
          float wv = wk[r * 3 + s];
#pragma unroll
          for (int p = 0; p < PXT; ++p) acc[k][p] += wv * in[r][s + p];
        }
    }
    __syncthreads();
  }
#pragma unroll
  for (int k = 0; k < KB; ++k) {
    float bv = bias[k0 + k];
    float4 v = make_float4(acc[k][0] + bv, acc[k][1] + bv, acc[k][2] + bv, acc[k][3] + bv);
    float* op = out + ((((size_t)n * 64 + (k0 + k)) * 224 + (h0 + th)) * 224 + (w0 + tw * PXT));
    *reinterpret_cast<float4*>(op) = v;
  }
}

extern "C" void kernel_launch(void* const* d_in, const int* in_sizes, int n_in,
                              void* d_out, int out_size, void* d_ws, size_t ws_size,
                              hipStream_t stream) {
  const float* x = (const float*)d_in[0];
  const float* W = (const float*)d_in[1];
  const float* b = (const float*)d_in[2];
  float* out = (float*)d_out;

  const size_t WT_BYTES = (size_t)9 * 64 * 64 * sizeof(unsigned short);   // 73728
  const size_t XT_BYTES = (size_t)16 * HW * 64 * sizeof(unsigned short);  // 102.76 MB

  if (ws_size >= WT_BYTES + XT_BYTES) {
    unsigned short* wt = (unsigned short*)d_ws;
    unsigned short* xt = (unsigned short*)((char*)d_ws + WT_BYTES);  // 128B-aligned
    build_wt<<<144, 256, 0, stream>>>(W, wt);
    pack_xt<<<16 * 196, 256, 0, stream>>>(x, xt);
    conv3x3_nhwc<<<3584, 448, 0, stream>>>(xt, wt, b, out);
  } else if (ws_size >= WT_BYTES) {
    unsigned short* wt = (unsigned short*)d_ws;
    build_wt<<<144, 256, 0, stream>>>(W, wt);
    conv3x3_mfma_tile<<<1568, 256, 0, stream>>>(x, wt, b, out);
  } else {
    dim3 grid(7 * 7, 64 / KB, 16);
    conv3x3_direct<<<grid, 256, 0, stream>>>(x, W, b, out);
  }
}